// Round 4
// baseline (91.587 us; speedup 1.0000x reference)
//
#include <hip/hip_runtime.h>

#define TEMP 0.7f
#define LOG2E 1.4426950408889634f
#define LN2 0.6931471805599453f
#define NPIX 8192
#define CDIM 128
// sqrt(LOG2E / TEMP): fold exp2-conversion + temperature into bf16 operands
#define FSCALE 1.4356161f
// exp(1/TEMP) = exp(diag) since features are L2-normalized (|F|^2 == 1)
#define EXPDIAG 4.1727352f

typedef __bf16 v8bf __attribute__((ext_vector_type(8)));
typedef float f32x4 __attribute__((ext_vector_type(4)));

// workspace layout (float offsets)
#define OFF_ROWSUM 0            // 8192 floats
#define OFF_G      8192         // 4*128 floats
#define OFF_COUNTS 8704         // int[4]
#define OFF_ACC    8708         // 1 float
#define OFF_DONE   8709         // 1 int
#define OFF_ZERON  8712         // zero the first OFF_ZERON floats
#define OFF_SWF    8960         // NPIX*CDIM bf16

__global__ __launch_bounds__(256) void k0_zero(float* __restrict__ w) {
    const int i = blockIdx.x * 256 + threadIdx.x;
    if (i < OFF_ZERON) w[i] = 0.0f;
}

// Transpose-build: coalesced feats reads -> LDS tile (128c x 32p, pad 33),
// then emit swizzled bf16 MFMA fragments, class sums G, counts.
// 256 blocks (1/CU), all LDS access <=2-way bank aliasing (free).
__global__ __launch_bounds__(256) void k1_build(
    const float* __restrict__ feats, const int* __restrict__ labels,
    v8bf* __restrict__ swf, float* __restrict__ G, int* __restrict__ counts)
{
    __shared__ float lds[128][33];
    __shared__ int lab_l[32];
    __shared__ float cs[2][4][128];

    const int t = threadIdx.x;
    const int bp = blockIdx.x >> 5;   // b' = row-block in concat order, 0..7
    const int pc = blockIdx.x & 31;   // 32-pixel chunk
    const int b = bp & 3, v = bp >> 2;
    const int bv = b * 2 + v;         // index into feats/labels batch dim
    const int p0 = pc * 32;
    const int nbase = bp * 1024 + p0;

    const float* src = feats + (size_t)bv * CDIM * 1024 + p0;
    const int px = t & 31, c8 = t >> 5;   // 8 channels per pass
#pragma unroll
    for (int i = 0; i < 16; i++) {
        const int c = i * 8 + c8;
        lds[c][px] = src[c * 1024 + px];
    }
    // labels + counts
    if (t < 32) {
        const int lab = labels[bv * 1024 + p0 + t];
        lab_l[t] = lab;
#pragma unroll
        for (int k = 0; k < 4; k++) {
            unsigned long long m = __ballot(lab == k);
            if (t == 0) atomicAdd(&counts[k], (int)__popcll(m));
        }
    }
    __syncthreads();

    // per-class partial sums over this block's 32 pixels
    {
        const int cw = t & 127, h = t >> 7;
        float s0 = 0.f, s1 = 0.f, s2 = 0.f, s3 = 0.f;
#pragma unroll
        for (int i = 0; i < 16; i++) {
            const int nl = h * 16 + i;
            const int lab = lab_l[nl];
            const float f = lds[cw][nl];
            s0 += (lab == 0) ? f : 0.f;
            s1 += (lab == 1) ? f : 0.f;
            s2 += (lab == 2) ? f : 0.f;
            s3 += (lab == 3) ? f : 0.f;
        }
        cs[h][0][cw] = s0; cs[h][1][cw] = s1;
        cs[h][2][cw] = s2; cs[h][3][cw] = s3;
    }
    __syncthreads();
    if (t < 128) {
#pragma unroll
        for (int k = 0; k < 4; k++)
            atomicAdd(&G[k * CDIM + t], cs[0][k][t] + cs[1][k][t]);
    }

    // swizzled bf16 fragment writes:
    // frag (ctg*4+kk), element q*16+r holds F[ctg*16+r][kk*32+q*8+j]*FSCALE
#pragma unroll
    for (int i2 = 0; i2 < 2; i2++) {
        const int slot = i2 * 256 + t;
        const int f = slot >> 6, l = slot & 63;
        const int ctl = f >> 2, kk = f & 3;
        const int q = l >> 4, r = l & 15;
        const int nl = ctl * 16 + r;
        const int c0 = kk * 32 + q * 8;
        v8bf val;
#pragma unroll
        for (int j = 0; j < 8; j++) val[j] = (__bf16)(lds[c0 + j][nl] * FSCALE);
        const int ctg = (nbase >> 4) + ctl;
        swf[(ctg * 4 + kk) * 64 + l] = val;
    }
}

// Fused S = F F^T (bf16 MFMA) + exp2 row-sum, SYMMETRIC: only upper-tri
// 256x256 tile-blocks (528 of 1024). Off-diag blocks add tile row-sums to
// rowsum[rows] and tile col-sums to rowsum[cols] (exp(S) is symmetric).
// Block = 4 waves; wave owns 64 rows (A-frags resident, 4x B reuse).
__global__ __launch_bounds__(256, 2) void k3_gemm_expsum(
    const v8bf* __restrict__ swf, float* __restrict__ rowsum)
{
    const int lane = threadIdx.x & 63;
    const int wave = threadIdx.x >> 6;
    // decode upper-triangular block (bi <= bj), 32 strips
    int rem = blockIdx.x, bi = 0;
    while (rem >= 32 - bi) { rem -= 32 - bi; bi++; }
    const int bj = bi + rem;
    const bool offdiag = (bj != bi);
    const int rowbase = bi * 256 + wave * 64;
    const int colbase = bj * 256;
    const int rt0 = rowbase >> 4;
    const int ct0 = colbase >> 4;

    v8bf a[4][4];
#pragma unroll
    for (int tt = 0; tt < 4; tt++)
#pragma unroll
        for (int kk = 0; kk < 4; kk++)
            a[tt][kk] = swf[((rt0 + tt) * 4 + kk) * 64 + lane];

    float rs[4][4];
#pragma unroll
    for (int tt = 0; tt < 4; tt++)
#pragma unroll
        for (int r = 0; r < 4; r++) rs[tt][r] = 0.f;

#pragma unroll
    for (int cl = 0; cl < 16; ++cl) {
        const int ct = ct0 + cl;
        const v8bf b0 = swf[(ct * 4 + 0) * 64 + lane];
        const v8bf b1 = swf[(ct * 4 + 1) * 64 + lane];
        const v8bf b2 = swf[(ct * 4 + 2) * 64 + lane];
        const v8bf b3 = swf[(ct * 4 + 3) * 64 + lane];
        float ccv = 0.f;
#pragma unroll
        for (int tt = 0; tt < 4; tt++) {
            f32x4 acc = {0.f, 0.f, 0.f, 0.f};
            acc = __builtin_amdgcn_mfma_f32_16x16x32_bf16(a[tt][0], b0, acc, 0, 0, 0);
            acc = __builtin_amdgcn_mfma_f32_16x16x32_bf16(a[tt][1], b1, acc, 0, 0, 0);
            acc = __builtin_amdgcn_mfma_f32_16x16x32_bf16(a[tt][2], b2, acc, 0, 0, 0);
            acc = __builtin_amdgcn_mfma_f32_16x16x32_bf16(a[tt][3], b3, acc, 0, 0, 0);
            // acc already = S * log2(e) thanks to FSCALE folding
#pragma unroll
            for (int r = 0; r < 4; r++) {
                const float e = __builtin_amdgcn_exp2f(acc[r]);
                rs[tt][r] += e;
                ccv += e;
            }
        }
        if (offdiag) {
            // col-sums of this 64-row x 16-col frag column
            ccv += __shfl_xor(ccv, 16, 64);
            ccv += __shfl_xor(ccv, 32, 64);
            if (lane < 16)
                atomicAdd(&rowsum[colbase + cl * 16 + lane], ccv);
        }
    }

    // row-sums: reduce across the 16 lanes of each C/D column group
#pragma unroll
    for (int m = 1; m < 16; m <<= 1)
#pragma unroll
        for (int tt = 0; tt < 4; tt++)
#pragma unroll
            for (int r = 0; r < 4; r++)
                rs[tt][r] += __shfl_xor(rs[tt][r], m, 64);

    if ((lane & 15) == 0) {
        const int g = lane >> 4;
#pragma unroll
        for (int tt = 0; tt < 4; tt++)
#pragma unroll
            for (int r = 0; r < 4; r++)
                atomicAdd(&rowsum[rowbase + tt * 16 + g * 4 + r], rs[tt][r]);
    }
}

// Per-anchor loss + final divide (last block). Block = 4 waves over 64
// anchors (one anchor per lane, p-coalesced feats reads); each wave covers
// 32 channels; LDS combine; one atomicAdd per block.
__global__ __launch_bounds__(256) void k4_loss(
    const float* __restrict__ feats, const int* __restrict__ labels,
    const float* __restrict__ G, const int* __restrict__ counts,
    const float* __restrict__ rowsum, float* __restrict__ acc,
    int* __restrict__ done, float* __restrict__ out)
{
    __shared__ float pd[4][64];
    const int t = threadIdx.x, lane = t & 63, w = t >> 6;
    const int n0 = blockIdx.x * 64;
    const int bp = n0 >> 10, p0 = n0 & 1023;
    const int bv = ((bp & 3) << 1) + (bp >> 2);
    const int p = p0 + lane;
    const int lab = labels[(bv << 10) + p];

    const float* src = feats + (((size_t)bv * CDIM + w * 32) << 10) + p;
    const float* g0p = G + w * 32;
    float dot = 0.f;
#pragma unroll 8
    for (int c = 0; c < 32; ++c) {
        const float f = src[(size_t)c << 10];
        const float g0 = g0p[c], g1 = g0p[CDIM + c];
        const float g2 = g0p[2 * CDIM + c], g3 = g0p[3 * CDIM + c];
        const float g = (lab == 1) ? g1 : (lab == 2) ? g2 : (lab == 3) ? g3 : g0;
        dot += f * g;
    }
    pd[w][lane] = dot;
    __syncthreads();
    if (w == 0) {
        const float d = pd[0][lane] + pd[1][lane] + pd[2][lane] + pd[3][lane];
        float loss = 0.f;
        if (lab != 0) {
            const float num = (d - 1.0f) * (1.0f / TEMP);
            const float den = rowsum[n0 + lane] - EXPDIAG;
            const float cnt = (float)(counts[lab] - 1);
            loss = __builtin_amdgcn_logf(den) * LN2 - num / cnt;
        }
#pragma unroll
        for (int m = 1; m < 64; m <<= 1) loss += __shfl_xor(loss, m, 64);
        if (lane == 0) {
            atomicAdd(acc, loss);
            __threadfence();
            const int old = atomicAdd(done, 1);
            if (old == 127) {
                const float tot = atomicAdd(acc, 0.0f);
                const int nv = NPIX - counts[0];
                out[0] = (nv > 0) ? tot / (float)nv : 0.0f;
            }
        }
    }
}

extern "C" void kernel_launch(void* const* d_in, const int* in_sizes, int n_in,
                              void* d_out, int out_size, void* d_ws, size_t ws_size,
                              hipStream_t stream) {
    const float* feats = (const float*)d_in[0];
    const int* labels = (const int*)d_in[1];
    float* out = (float*)d_out;
    float* W = (float*)d_ws;

    float* rowsum = W + OFF_ROWSUM;
    float* G      = W + OFF_G;
    int*   counts = (int*)(W + OFF_COUNTS);
    float* acc    = W + OFF_ACC;
    int*   done   = (int*)(W + OFF_DONE);
    v8bf*  swf    = (v8bf*)(W + OFF_SWF);

    k0_zero<<<(OFF_ZERON + 255) / 256, 256, 0, stream>>>(W);
    k1_build<<<256, 256, 0, stream>>>(feats, labels, swf, G, counts);
    k3_gemm_expsum<<<528, 256, 0, stream>>>(swf, rowsum);
    k4_loss<<<128, 256, 0, stream>>>(feats, labels, G, counts, rowsum, acc, done, out);
}